// Round 8
// baseline (62.860 us; speedup 1.0000x reference)
//
#include <hip/hip_runtime.h>
#include <math.h>

#define N 4096
#define D 64
#define NSLICE 8
#define JLEN 512          // N / NSLICE
#define CH 32             // j-chunk per iteration
#define NCHUNK 16         // JLEN / CH
#define SH 44.0f          // fixed softmax shift: exp(logit - 44); cancels in u/l

// LDS byte map (50 KB block):
//   S:   4 bufs x 8 KB  fp32 [64 rows][8 slots], slot XOR (row&7) via global pre-swizzle
//   Mt:  3 bufs x 4 KB  bf16, slot = kslot*64 + d   (lane-consecutive MFMA B reads)
//   E:   4 KB           bf16, slot = q*64 + (row^2q) (conflict-free write AND read)
//   scl: 2 KB           fp32 scale slice
#define S_OFF   0
#define MT_OFF  32768
#define E_OFF   45056
#define SCL_OFF 49152
#define LDS_BYTES 51200

typedef short bf16x8 __attribute__((ext_vector_type(8)));
typedef float f32x4  __attribute__((ext_vector_type(4)));

__device__ __forceinline__ unsigned short f2bf(float x) {   // RNE f32->bf16
    unsigned int u = __float_as_uint(x);
    u += 0x7FFFu + ((u >> 16) & 1u);
    return (unsigned short)(u >> 16);
}
__device__ __forceinline__ float bf2f(unsigned short h) {
    return __uint_as_float(((unsigned int)h) << 16);
}

// async global->LDS DMA, 16B per lane; LDS dest wave-uniform base + lane*16.
__device__ __forceinline__ void gld16(const void* g, void* l) {
    __builtin_amdgcn_global_load_lds(
        (const __attribute__((address_space(1))) void*)g,
        (__attribute__((address_space(3))) void*)l,
        16, 0, 0);
}

// Barrier that waits only LDS ops; global/DMA loads stay in flight across it.
__device__ __forceinline__ void lds_barrier() {
    asm volatile("s_waitcnt lgkmcnt(0)" ::: "memory");
    __builtin_amdgcn_s_barrier();
    asm volatile("" ::: "memory");
}
__device__ __forceinline__ void plain_barrier() {
    asm volatile("" ::: "memory");
    __builtin_amdgcn_s_barrier();
    asm volatile("" ::: "memory");
}

// ---------------- Kernel A: per-row scale + Mt[d][j] = bf16(linear(msg)) ----------------
__global__ __launch_bounds__(256) void prep_kernel(
    const float* __restrict__ embed,
    const float* __restrict__ degd, const float* __restrict__ degt,
    const float* __restrict__ W1, const float* __restrict__ b1,
    const float* __restrict__ W2, const float* __restrict__ b2,
    const float* __restrict__ W3, const float* __restrict__ b3,
    float* __restrict__ scale, unsigned short* __restrict__ Mt)
{
    const int rel = blockIdx.y;
    const float* W  = (rel == 0) ? W1 : (rel == 1 ? W2 : W3);
    const float* bb = (rel == 0) ? b1 : (rel == 1 ? b2 : b3);
    __shared__ float Wl[D][D + 1];
    __shared__ float xr[4][D];
    const int tid = threadIdx.x;
    for (int idx = tid; idx < D * D; idx += 256)
        Wl[idx >> 6][idx & 63] = W[idx];
    const int w = tid >> 6, d = tid & 63;
    const int i = blockIdx.x * 4 + w;

    float msg, term, xsrc, dga, dgb;
    if (rel == 0) {
        float s = embed[(size_t)i * D + d];
        msg = s + s * s; term = s * msg; xsrc = msg;
        dga = degd[i]; dgb = degd[i];
    } else if (rel == 1) {
        float s = embed[(size_t)i * D + d];
        float t = embed[(size_t)(N + i) * D + d];
        msg = t + s * t; term = s * msg; xsrc = msg;
        dga = degd[i]; dgb = degt[i];
    } else {
        float t = embed[(size_t)(N + i) * D + d];
        msg = t + t * t; term = t * msg; xsrc = t;   // similar uses linear(task)!
        dga = degt[i]; dgb = degt[i];
    }
    float dot = term;
    #pragma unroll
    for (int mm = 1; mm < 64; mm <<= 1) dot += __shfl_xor(dot, mm);
    if (d == 0)
        scale[rel * N + i] = dot / (sqrtf(dga * dgb + 1e-8f) * 8.0f);  // sqrt(D)=8

    xr[w][d] = xsrc;
    __syncthreads();
    float o = bb[d];
    #pragma unroll 8
    for (int k = 0; k < D; ++k) o += xr[w][k] * Wl[d][k];
    Mt[((size_t)rel * D + d) * N + i] = f2bf(o);   // transposed, bf16
}

// ------------- Kernel B: fixed-shift softmax x (att @ M) via bf16 MFMA -------------
// grid (64 rowgroups, 3 rels, NSLICE slices), block 256 (4 waves), 3 blocks/CU.
// All staging via global_load_lds DMA: S 4-deep (issue c+3), Mt 3-deep (c+2);
// steady-state s_waitcnt vmcnt(5) -- never drain in the main loop.
__global__ __launch_bounds__(256, 3) void attn_kernel(
    const float* __restrict__ S0, const float* __restrict__ S1, const float* __restrict__ S2,
    const float* __restrict__ scale, const unsigned short* __restrict__ Mt,
    unsigned short* __restrict__ Up, float* __restrict__ lp)
{
    __shared__ __align__(16) char LDS[LDS_BYTES];
    const int rg = blockIdx.x, rel = blockIdx.y, sl = blockIdx.z;
    const float* S = (rel == 0) ? S0 : (rel == 1 ? S1 : S2);
    const unsigned short* Mtr = Mt + (size_t)rel * D * N;
    const int tid = threadIdx.x;
    const int lane = tid & 63, wave = tid >> 6;
    const int row = tid >> 2, q = tid & 3;      // e-phase: 4 lanes per row, 8 cols each
    const int j0 = sl * JLEN;

    // per-thread pre-swizzled global sources for the DMAs
    const int srow = tid >> 3, sslot = tid & 7;
    const int sx = (sslot ^ (srow & 7)) * 4;               // 4 floats per 16B slot
    const float* s0p = S + (size_t)(rg * 64 + srow) * N + j0 + sx;
    const float* s1p = S + (size_t)(rg * 64 + 32 + srow) * N + j0 + sx;
    const unsigned short* mtp = Mtr + (size_t)(tid & 63) * N + j0 + wave * 8;
    // wave-uniform LDS DMA bases
    char* sldsw = LDS + S_OFF + wave * 1024;
    char* mldsw = LDS + MT_OFF + wave * 1024;

#define ISSUE_S(cc, bb) do {                                \
        gld16(s0p + (cc) * CH, sldsw + (bb) * 8192);        \
        gld16(s1p + (cc) * CH, sldsw + (bb) * 8192 + 4096); \
    } while (0)
#define ISSUE_M(cc, bb) gld16(mtp + (cc) * CH, mldsw + (bb) * 4096)

    // prologue: stage scale slice, then DMA queue [Mt0,S0,S0,Mt1,S1,S1,S2,S2]
    for (int k = tid; k < JLEN; k += 256)
        *(float*)(LDS + SCL_OFF + k * 4) = scale[rel * N + j0 + k];
    asm volatile("" ::: "memory");
    ISSUE_M(0, 0); ISSUE_S(0, 0);
    ISSUE_M(1, 1); ISSUE_S(1, 1);
    ISSUE_S(2, 2);
    lds_barrier();   // scl visible; 8 DMAs in flight

    const int wbase = wave * 16;
    const int lrow  = lane & 15;   // A-row / B-col / C-col within tile
    const int lk    = lane >> 4;   // k-slot / C row-group
    float l = 0.f;
    f32x4 acc[4];
    #pragma unroll
    for (int ct = 0; ct < 4; ++ct) {
        acc[ct][0] = 0.f; acc[ct][1] = 0.f; acc[ct][2] = 0.f; acc[ct][3] = 0.f;
    }

    int bm = 0;   // Mt buffer of chunk c (c % 3)
    for (int c = 0; c < NCHUNK; ++c) {
        // wait: chunk c landed; keep newest 5 [S(c+1)x2? -> Mt(c+1),S(c+2)x2,...] in flight
        if (c < NCHUNK - 2)       asm volatile("s_waitcnt vmcnt(5)" ::: "memory");
        else if (c == NCHUNK - 2) asm volatile("s_waitcnt vmcnt(3)" ::: "memory");
        else                      asm volatile("s_waitcnt vmcnt(0)" ::: "memory");
        plain_barrier();   // all waves' chunk-c DMAs landed; prior readers done

        // issue: Mt(c+2) then S(c+3) (order matters for the FIFO wait counts)
        if (c + 2 < NCHUNK) { int t = bm + 2; if (t >= 3) t -= 3; ISSUE_M(c + 2, t); }
        if (c + 3 < NCHUNK) ISSUE_S(c + 3, (c + 3) & 3);

        // ---- e-phase: read S tile (un-swizzle by XOR), exp, pack bf16 -> E ----
        {
            const char* sb = LDS + S_OFF + (c & 3) * 8192;
            const int r7 = row & 7;
            const f32x4 va = *(const f32x4*)(sb + row * 128 + (((2 * q)     ^ r7) << 4));
            const f32x4 vb = *(const f32x4*)(sb + row * 128 + (((2 * q + 1) ^ r7) << 4));
            const f32x4 ca = *(const f32x4*)(LDS + SCL_OFF + c * 128 + q * 32);
            const f32x4 cb = *(const f32x4*)(LDS + SCL_OFF + c * 128 + q * 32 + 16);
            float e[8];
            e[0] = __expf(fmaf(va[0], ca[0], -SH));
            e[1] = __expf(fmaf(va[1], ca[1], -SH));
            e[2] = __expf(fmaf(va[2], ca[2], -SH));
            e[3] = __expf(fmaf(va[3], ca[3], -SH));
            e[4] = __expf(fmaf(vb[0], cb[0], -SH));
            e[5] = __expf(fmaf(vb[1], cb[1], -SH));
            e[6] = __expf(fmaf(vb[2], cb[2], -SH));
            e[7] = __expf(fmaf(vb[3], cb[3], -SH));
            #pragma unroll
            for (int k = 0; k < 8; ++k) l += e[k];
            union { unsigned short h[8]; uint4 v; } pk;
            #pragma unroll
            for (int k = 0; k < 8; ++k) pk.h[k] = f2bf(e[k]);
            // E slot = q*64 + (row ^ 2q): conflict-free write and read
            *(uint4*)(LDS + E_OFF + ((q * 64 + (row ^ (2 * q))) << 4)) = pk.v;
        }

        lds_barrier();   // E visible; DMAs stay in flight

        // ---- MFMA: 4x mfma_16x16x32, conflict-free fragment reads ----
        {
            const char* mb = LDS + MT_OFF + bm * 4096;
            const bf16x8 a = *(const bf16x8*)(
                LDS + E_OFF + ((lk * 64 + ((wbase + lrow) ^ (2 * lk))) << 4));
            #pragma unroll
            for (int ct = 0; ct < 4; ++ct) {
                const bf16x8 b = *(const bf16x8*)(mb + ((lk * 64 + ct * 16 + lrow) << 4));
                acc[ct] = __builtin_amdgcn_mfma_f32_16x16x32_bf16(a, b, acc[ct], 0, 0, 0);
            }
        }
        // no trailing barrier: next iter's top barrier orders buffer reuse

        bm = bm + 1; if (bm == 3) bm = 0;
    }
#undef ISSUE_S
#undef ISSUE_M

    // ---- epilogue: repack partials into LDS (S buf region, now dead) ----
    unsigned short* R = (unsigned short*)LDS;
    #pragma unroll
    for (int ct = 0; ct < 4; ++ct)
        #pragma unroll
        for (int r = 0; r < 4; ++r) {
            const int ri = wbase + lk * 4 + r;   // C/D: row=(lane>>4)*4+reg
            R[ri * 64 + ct * 16 + lrow] = f2bf(acc[ct][r]);
        }
    lds_barrier();
    const size_t pbase = (size_t)((rel * 64 + rg) * NSLICE + sl);
    unsigned short* up = Up + pbase * 4096;
    {
        const uint4* src = (const uint4*)R;
        uint4*       dst = (uint4*)up;
        dst[tid]       = src[tid];
        dst[256 + tid] = src[256 + tid];
    }
    l += __shfl_xor(l, 1);
    l += __shfl_xor(l, 2);
    if (q == 0) lp[pbase * 64 + row] = l;
}

// ---------------- Kernel C: combine partials + residual + linear(W3) + leaky-relu ----------------
__device__ __forceinline__ float combine_row(
    const unsigned short* __restrict__ Up, const float* __restrict__ lp,
    int rel, int i, int d)
{
    const int rg = i >> 6, r = i & 63;
    const int base = (rel * 64 + rg) * NSLICE;
    float lt = 0.f, u = 0.f;
    #pragma unroll
    for (int p = 0; p < NSLICE; ++p) {
        lt += lp[(base + p) * 64 + r];
        u  += bf2f(Up[(size_t)(base + p) * 4096 + r * 64 + d]);
    }
    return u / lt;   // fixed shift cancels; lt > 0 always
}

__global__ __launch_bounds__(256) void final_kernel(
    const float* __restrict__ embed,
    const unsigned short* __restrict__ Up, const float* __restrict__ lp,
    const float* __restrict__ W3, const float* __restrict__ b3,
    float* __restrict__ out)
{
    __shared__ float Wl[D][D + 1];
    __shared__ float xs[4][D];
    const int tid = threadIdx.x;
    for (int idx = tid; idx < D * D; idx += 256)
        Wl[idx >> 6][idx & 63] = W3[idx];
    const int w = tid >> 6, d = tid & 63;
    const int g = blockIdx.x * 4 + w;   // 0..8191

    float x = embed[(size_t)g * D + d];
    if (g < N) {
        x += combine_row(Up, lp, 0, g, d);
        x += combine_row(Up, lp, 1, g, d);
    } else {
        x += combine_row(Up, lp, 2, g - N, d);
    }
    xs[w][d] = x;
    __syncthreads();
    float o = b3[d];
    #pragma unroll 8
    for (int k = 0; k < D; ++k) o += xs[w][k] * Wl[d][k];
    o = (o > 0.f) ? o : 0.2f * o;
    out[(size_t)g * D + d] = o;
}

extern "C" void kernel_launch(void* const* d_in, const int* in_sizes, int n_in,
                              void* d_out, int out_size, void* d_ws, size_t ws_size,
                              hipStream_t stream)
{
    const float* embed = (const float*)d_in[0];
    // d_in[1..3] = adj_* (unused by the reference)
    const float* Sc   = (const float*)d_in[4];
    const float* Si   = (const float*)d_in[5];
    const float* Ss   = (const float*)d_in[6];
    const float* degd = (const float*)d_in[7];
    const float* degt = (const float*)d_in[8];
    const float* W1 = (const float*)d_in[9];
    const float* b1 = (const float*)d_in[10];
    const float* W2 = (const float*)d_in[11];
    const float* b2 = (const float*)d_in[12];
    const float* W3 = (const float*)d_in[13];
    const float* b3 = (const float*)d_in[14];
    float* out = (float*)d_out;

    // ws layout:
    //   scale: 3*N              = 12288 f32
    //   lp:    3*64*NSLICE*64   = 98304 f32
    //   Mt:    3*D*N            = 786432 ushort
    //   Up:    3*64*NSLICE*4096 = 6291456 ushort          total ~14.6 MB
    float* ws    = (float*)d_ws;
    float* scale = ws;
    float* lp    = ws + 12288;
    unsigned short* Mt = (unsigned short*)(lp + 98304);
    unsigned short* Up = Mt + 786432;

    prep_kernel<<<dim3(N / 4, 3), 256, 0, stream>>>(
        embed, degd, degt, W1, b1, W2, b2, W3, b3, scale, Mt);
    attn_kernel<<<dim3(64, 3, NSLICE), 256, 0, stream>>>(
        Sc, Si, Ss, scale, Mt, Up, lp);
    final_kernel<<<dim3(2 * N / 4), 256, 0, stream>>>(
        embed, Up, lp, W3, b3, out);
}